// Round 10
// baseline (354.360 us; speedup 1.0000x reference)
//
#include <hip/hip_runtime.h>
#include <hip/hip_bf16.h>

// GATNet v9: single-pass 128x256 gemm1 (A read once) with fused attention
// logits in the epilogue (k_al1 deleted, no atomics: each head's 32 cols live
// inside one wave's column span), k_prep fuses hist+W1t+W2t, scanB+C merged.
// 9 dispatches (was 14).

#define LRELU(x) ((x) > 0.f ? (x) : 0.2f * (x))

typedef __attribute__((ext_vector_type(8))) short short8;
typedef __attribute__((ext_vector_type(8))) unsigned short ushort8;
typedef __attribute__((ext_vector_type(4))) float f32x4;

__device__ inline unsigned short f2b(float f) {
    __hip_bfloat16 h = __float2bfloat16(f);
    return *reinterpret_cast<unsigned short*>(&h);
}
__device__ inline float b2f(unsigned short u) {
    __hip_bfloat16 h;
    *reinterpret_cast<unsigned short*>(&h) = u;
    return __bfloat162float(h);
}

// ---------------- fused prep: hist + W1 transpose-cast + W2 transpose-cast --

__global__ __launch_bounds__(256) void k_prep(const int* __restrict__ dst, int* deg, int E,
                                              const float* __restrict__ W1,
                                              unsigned short* __restrict__ W1t,
                                              const float* __restrict__ W2,
                                              unsigned short* __restrict__ W2t,
                                              int HB) {
    int b = blockIdx.x, t = threadIdx.x;
    if (b < HB) {
        int i = b * 256 + t;
        if (i < E) atomicAdd(&deg[dst[i]], 1);
    } else if (b < HB + 256) {
        int k = b - HB;
        W1t[t * 256 + k] = f2b(W1[k * 256 + t]);
    } else {
        int nn = b - HB - 256;  // 0..15
        W2t[nn * 256 + t] = f2b(W2[t * 16 + nn]);
    }
}

// ---------------- scan phase A: block-local ----------------

__global__ __launch_bounds__(256) void k_scanA(const int* __restrict__ deg,
                                               int* __restrict__ tmp,
                                               int* __restrict__ blocksum, int n) {
    __shared__ int sc[256];
    int b = blockIdx.x, t = threadIdx.x;
    int i = b * 256 + t;
    int v = (i < n) ? deg[i] + 1 : 0;   // +1: self loop
    sc[t] = v;
    __syncthreads();
    for (int off = 1; off < 256; off <<= 1) {
        int x = 0;
        if (t >= off) x = sc[t - off];
        __syncthreads();
        sc[t] += x;
        __syncthreads();
    }
    if (i < n) tmp[i] = sc[t] - v;
    if (t == 255) blocksum[b] = sc[255];
}

// ---------------- scan phase B+C merged: every block re-scans blocksums -----

__global__ __launch_bounds__(256) void k_scanC(const int* __restrict__ tmp,
                                               const int* __restrict__ blocksum,
                                               int* __restrict__ offs,
                                               int* __restrict__ cursor,
                                               int n, int P, int nb) {
    __shared__ int sc[256];
    __shared__ int base;
    int b = blockIdx.x, t = threadIdx.x;
    int v = (t < nb) ? blocksum[t] : 0;
    sc[t] = v;
    __syncthreads();
    for (int off = 1; off < 256; off <<= 1) {
        int x = 0;
        if (t >= off) x = sc[t - off];
        __syncthreads();
        sc[t] += x;
        __syncthreads();
    }
    if (t == 0) base = (b == 0) ? 0 : sc[b - 1];
    __syncthreads();
    int i = b * 256 + t;
    if (i < n) {
        int o = tmp[i] + base;
        offs[i] = o;
        cursor[i] = o;
    }
    if (b == 0 && t == 0) offs[n] = P;
}

__global__ void k_scatter(const int* __restrict__ src, const int* __restrict__ dst,
                          int* cursor, int* __restrict__ csr, int E, int n) {
    int i = blockIdx.x * blockDim.x + threadIdx.x;
    int s, d;
    if (i < E) {
        s = src[i];
        d = dst[i];
    } else if (i < E + n) {
        s = i - E;
        d = s;
    } else {
        return;
    }
    int p = atomicAdd(&cursor[d], 1);
    csr[p] = s;
}

// ---------------- GEMM1 (MFMA bf16) 128x256/block + fused al logits ---------
// One block covers ALL 256 output cols: A read once. Wave w: rows (w&1)*64,
// cols (w>>1)*128. head = col>>5 lies entirely within a wave's j-pair, so
// als1/ald1 computed exactly from fp32 acc via width-16 shuffle, no atomics.

__global__ __launch_bounds__(256) void k_gemm1(const float* __restrict__ A,
                                               const unsigned short* __restrict__ Wt,
                                               unsigned short* __restrict__ h1b,
                                               const float* __restrict__ asrc,
                                               const float* __restrict__ adst,
                                               float* __restrict__ als,
                                               float* __restrict__ ald, int M) {
    __shared__ unsigned short As[128][40];
    __shared__ unsigned short Bs[256][40];
    int t = threadIdx.x;
    int r0 = blockIdx.x * 128;
    int srow = t >> 1, shalf = t & 1;
    int lane = t & 63, w = t >> 6;
    int lane15 = lane & 15, quad = lane >> 4;
    int rbw = (w & 1) * 64, cbw = (w >> 1) * 128;

    f32x4 acc[4][8];
#pragma unroll
    for (int i = 0; i < 4; i++)
#pragma unroll
        for (int j = 0; j < 8; j++) acc[i][j] = (f32x4)0.f;

    for (int k0 = 0; k0 < 256; k0 += 32) {
        {
            int row = r0 + srow;
            ushort8 p0, p1;
            if (row < M) {
                const float4* sp = (const float4*)&A[(size_t)row * 256 + k0 + shalf * 16];
                float4 f0 = sp[0], f1 = sp[1], f2 = sp[2], f3 = sp[3];
                p0[0] = f2b(f0.x); p0[1] = f2b(f0.y); p0[2] = f2b(f0.z); p0[3] = f2b(f0.w);
                p0[4] = f2b(f1.x); p0[5] = f2b(f1.y); p0[6] = f2b(f1.z); p0[7] = f2b(f1.w);
                p1[0] = f2b(f2.x); p1[1] = f2b(f2.y); p1[2] = f2b(f2.z); p1[3] = f2b(f2.w);
                p1[4] = f2b(f3.x); p1[5] = f2b(f3.y); p1[6] = f2b(f3.z); p1[7] = f2b(f3.w);
            } else {
                p0 = (ushort8)0; p1 = (ushort8)0;
            }
            *(ushort8*)&As[srow][shalf * 16] = p0;
            *(ushort8*)&As[srow][shalf * 16 + 8] = p1;
            // B: Wt row t (output col t), k0..k0+31
            const ushort8* bp = (const ushort8*)&Wt[(size_t)t * 256 + k0];
            *(ushort8*)&Bs[t][0] = bp[0];
            *(ushort8*)&Bs[t][8] = bp[1];
            *(ushort8*)&Bs[t][16] = bp[2];
            *(ushort8*)&Bs[t][24] = bp[3];
        }
        __syncthreads();
        short8 af[4], bf[8];
#pragma unroll
        for (int i = 0; i < 4; i++)
            af[i] = *(const short8*)&As[rbw + i * 16 + lane15][quad * 8];
#pragma unroll
        for (int j = 0; j < 8; j++)
            bf[j] = *(const short8*)&Bs[cbw + j * 16 + lane15][quad * 8];
#pragma unroll
        for (int i = 0; i < 4; i++)
#pragma unroll
            for (int j = 0; j < 8; j++)
                acc[i][j] = __builtin_amdgcn_mfma_f32_16x16x32_bf16(af[i], bf[j], acc[i][j], 0, 0, 0);
        __syncthreads();
    }

    // epilogue: h1b writes + fused attention logits
    float asv[8], adv[8];
#pragma unroll
    for (int j = 0; j < 8; j++) {
        asv[j] = asrc[cbw + j * 16 + lane15];
        adv[j] = adst[cbw + j * 16 + lane15];
    }
    int hbase0 = cbw >> 5;  // 0 or 4
#pragma unroll
    for (int i = 0; i < 4; i++) {
        int rowb = r0 + rbw + i * 16 + quad * 4;
#pragma unroll
        for (int j = 0; j < 8; j++) {
            int col = cbw + j * 16 + lane15;
#pragma unroll
            for (int r = 0; r < 4; r++) {
                int row = rowb + r;
                if (row < M) h1b[(size_t)row * 256 + col] = f2b(acc[i][j][r]);
            }
        }
#pragma unroll
        for (int m = 0; m < 4; m++) {
#pragma unroll
            for (int r = 0; r < 4; r++) {
                float ps = acc[i][2 * m][r] * asv[2 * m] + acc[i][2 * m + 1][r] * asv[2 * m + 1];
                float pd = acc[i][2 * m][r] * adv[2 * m] + acc[i][2 * m + 1][r] * adv[2 * m + 1];
#pragma unroll
                for (int off = 1; off < 16; off <<= 1) {
                    ps += __shfl_xor(ps, off, 16);
                    pd += __shfl_xor(pd, off, 16);
                }
                int row = rowb + r;
                if (lane15 == 0 && row < M) {
                    als[(size_t)row * 8 + hbase0 + m] = ps;
                    ald[(size_t)row * 8 + hbase0 + m] = pd;
                }
            }
        }
    }
}

// ---------------- layer-1 aggregate: fused weights, 4-deep gather pipeline --

__global__ __launch_bounds__(128) void k_agg1(const int* __restrict__ csr,
                                              const int* __restrict__ offs,
                                              const float* __restrict__ als,
                                              const float* __restrict__ aldg,
                                              const unsigned short* __restrict__ h1b,
                                              const float* __restrict__ b1,
                                              unsigned short* __restrict__ x2b) {
    int v = blockIdx.x;
    int t = threadIdx.x;           // cols 2t,2t+1; head = t>>4
    int start = offs[v];
    int deg = offs[v + 1] - start;
    __shared__ float aldv[8];
    __shared__ int su[32];
    __shared__ float ws[8 * 33];
    if (t < 8) aldv[t] = aldg[v * 8 + t];
    __syncthreads();
    int h = t >> 4;
    const unsigned int* __restrict__ hbase = (const unsigned int*)h1b;
    float a0 = 0.f, a1 = 0.f, wsum = 0.f;
    for (int base = 0; base < deg; base += 32) {
        int cnt = min(32, deg - base);
        int cnt4 = (cnt + 3) & ~3;
        if (base) __syncthreads();
        if (t < cnt4) {
            if (t < cnt) {
                int u = csr[start + base + t];
                su[t] = u;
                const float4* ap = (const float4*)(als + (size_t)u * 8);
                float4 x0 = ap[0], x1 = ap[1];
                ws[0 * 33 + t] = __expf(LRELU(x0.x + aldv[0]));
                ws[1 * 33 + t] = __expf(LRELU(x0.y + aldv[1]));
                ws[2 * 33 + t] = __expf(LRELU(x0.z + aldv[2]));
                ws[3 * 33 + t] = __expf(LRELU(x0.w + aldv[3]));
                ws[4 * 33 + t] = __expf(LRELU(x1.x + aldv[4]));
                ws[5 * 33 + t] = __expf(LRELU(x1.y + aldv[5]));
                ws[6 * 33 + t] = __expf(LRELU(x1.z + aldv[6]));
                ws[7 * 33 + t] = __expf(LRELU(x1.w + aldv[7]));
            } else {
                su[t] = v;
#pragma unroll
                for (int k = 0; k < 8; k++) ws[k * 33 + t] = 0.f;
            }
        }
        __syncthreads();
        for (int e = 0; e < cnt4; e += 4) {
            int u0 = su[e + 0], u1 = su[e + 1], u2 = su[e + 2], u3 = su[e + 3];
            float w0 = ws[h * 33 + e + 0];
            float w1 = ws[h * 33 + e + 1];
            float w2 = ws[h * 33 + e + 2];
            float w3 = ws[h * 33 + e + 3];
            unsigned int pk0 = hbase[u0 * 128 + t];
            unsigned int pk1 = hbase[u1 * 128 + t];
            unsigned int pk2 = hbase[u2 * 128 + t];
            unsigned int pk3 = hbase[u3 * 128 + t];
            a0 += w0 * __uint_as_float(pk0 << 16);
            a1 += w0 * __uint_as_float(pk0 & 0xffff0000u);
            a0 += w1 * __uint_as_float(pk1 << 16);
            a1 += w1 * __uint_as_float(pk1 & 0xffff0000u);
            a0 += w2 * __uint_as_float(pk2 << 16);
            a1 += w2 * __uint_as_float(pk2 & 0xffff0000u);
            a0 += w3 * __uint_as_float(pk3 << 16);
            a1 += w3 * __uint_as_float(pk3 & 0xffff0000u);
            wsum += (w0 + w1) + (w2 + w3);
        }
    }
    const float2* b1v = (const float2*)b1;
    float2 bb = b1v[t];
    float inv = 1.0f / wsum;
    float o0 = a0 * inv + bb.x;
    float o1 = a1 * inv + bb.y;
    o0 = o0 > 0.f ? o0 : 0.f;
    o1 = o1 > 0.f ? o1 : 0.f;
    unsigned int opk = (unsigned int)f2b(o0) | ((unsigned int)f2b(o1) << 16);
    ((unsigned int*)(x2b + (size_t)v * 256))[t] = opk;
}

// ---------------- GEMM2 (MFMA) + fused layer-2 logits ----------------------

__global__ __launch_bounds__(256) void k_gemm2(const unsigned short* __restrict__ Xb,
                                               const unsigned short* __restrict__ W2t,
                                               const float* __restrict__ asrc,
                                               const float* __restrict__ adst,
                                               unsigned short* __restrict__ h2b,
                                               float* __restrict__ als,
                                               float* __restrict__ ald, int n) {
    int t = threadIdx.x;
    int lane = t & 63, w = t >> 6;
    int lane15 = lane & 15, quad = lane >> 4;
    int row0 = blockIdx.x * 64 + w * 16;
    f32x4 acc = (f32x4)0.f;
#pragma unroll
    for (int k0 = 0; k0 < 256; k0 += 32) {
        short8 a = *(const short8*)&Xb[(size_t)(row0 + lane15) * 256 + k0 + quad * 8];
        short8 b = *(const short8*)&W2t[lane15 * 256 + k0 + quad * 8];
        acc = __builtin_amdgcn_mfma_f32_16x16x32_bf16(a, b, acc, 0, 0, 0);
    }
    float asv = asrc[lane15], adv = adst[lane15];
#pragma unroll
    for (int r = 0; r < 4; r++) {
        int row = row0 + quad * 4 + r;
        float hv = acc[r];
        float ps = hv * asv, pd = hv * adv;
#pragma unroll
        for (int off = 1; off < 16; off <<= 1) {
            ps += __shfl_xor(ps, off, 16);
            pd += __shfl_xor(pd, off, 16);
        }
        if (row < n) {
            h2b[(size_t)row * 16 + lane15] = f2b(hv);
            if (lane15 == 0) {
                als[row] = ps;
                ald[row] = pd;
            }
        }
    }
}

// ---------------- layer-2 aggregate (fused w) + log_softmax -----------------

__global__ __launch_bounds__(256) void k_agg2(const int* __restrict__ csr,
                                              const int* __restrict__ offs,
                                              const float* __restrict__ als,
                                              const float* __restrict__ aldg,
                                              const unsigned short* __restrict__ h2b,
                                              const float* __restrict__ b2,
                                              float* __restrict__ out, int n) {
    int v = blockIdx.x * 4 + (threadIdx.x >> 6);
    if (v >= n) return;
    int lane = threadIdx.x & 63;
    int start = offs[v];
    int deg = offs[v + 1] - start;
    float aldv = aldg[v];
    int c = lane & 15, q = lane >> 4;
    float acc = 0.f, wsum = 0.f;
    for (int e = q; e < deg; e += 4) {
        int u = csr[start + e];
        float x = als[u] + aldv;
        float wv = __expf(LRELU(x));
        acc += wv * b2f(h2b[(size_t)u * 16 + c]);
        wsum += wv;
    }
    acc += __shfl_xor(acc, 32, 64);
    acc += __shfl_xor(acc, 16, 64);
    wsum += __shfl_xor(wsum, 32, 64);
    wsum += __shfl_xor(wsum, 16, 64);
    float o = acc / wsum + b2[c];
    float mx = o;
#pragma unroll
    for (int off = 8; off; off >>= 1) mx = fmaxf(mx, __shfl_xor(mx, off, 16));
    float s = __expf(o - mx);
#pragma unroll
    for (int off = 8; off; off >>= 1) s += __shfl_xor(s, off, 16);
    float res = o - mx - __logf(s);
    if (q == 0) out[(size_t)v * 16 + c] = res;
}

// ---------------- launch ----------------

extern "C" void kernel_launch(void* const* d_in, const int* in_sizes, int n_in,
                              void* d_out, int out_size, void* d_ws, size_t ws_size,
                              hipStream_t stream) {
    const float* x = (const float*)d_in[0];
    const int* ei = (const int*)d_in[1];
    const float* W1 = (const float*)d_in[2];
    const float* asrc1 = (const float*)d_in[3];
    const float* adst1 = (const float*)d_in[4];
    const float* b1 = (const float*)d_in[5];
    const float* W2 = (const float*)d_in[6];
    const float* asrc2 = (const float*)d_in[7];
    const float* adst2 = (const float*)d_in[8];
    const float* b2 = (const float*)d_in[9];
    float* out = (float*)d_out;

    int n = in_sizes[0] / 256;   // 50000
    int E = in_sizes[1] / 2;     // 800000
    int P = E + n;
    const int* src = ei;
    const int* dst = ei + E;
    int NB = (n + 255) / 256;    // 196
    int HB = (E + 255) / 256;    // 3125

    char* p = (char*)d_ws;
    auto alloc = [&](size_t bytes) {
        void* r = (void*)p;
        p += (bytes + 255) & ~(size_t)255;
        return r;
    };
    unsigned short* h1b = (unsigned short*)alloc((size_t)n * 256 * 2);
    unsigned short* x2b = (unsigned short*)alloc((size_t)n * 256 * 2);
    unsigned short* W1t = (unsigned short*)alloc((size_t)256 * 256 * 2);
    unsigned short* W2t = (unsigned short*)alloc((size_t)16 * 256 * 2);
    float* als1 = (float*)alloc((size_t)n * 8 * 4);
    float* ald1 = (float*)alloc((size_t)n * 8 * 4);
    unsigned short* h2b = (unsigned short*)alloc((size_t)n * 16 * 2);
    float* als2 = (float*)alloc((size_t)n * 4);
    float* ald2 = (float*)alloc((size_t)n * 4);
    int* deg = (int*)alloc((size_t)n * 4);
    int* offs = (int*)alloc((size_t)(n + 1) * 4);
    int* cursor = (int*)alloc((size_t)n * 4);
    int* stmp = (int*)alloc((size_t)n * 4);
    int* blocksum = (int*)alloc((size_t)NB * 4);
    int* csr = (int*)alloc((size_t)P * 4);

    // CSR build + weight prep (fused)
    hipMemsetAsync(deg, 0, (size_t)n * 4, stream);
    k_prep<<<HB + 256 + 16, 256, 0, stream>>>(dst, deg, E, W1, W1t, W2, W2t, HB);
    k_scanA<<<NB, 256, 0, stream>>>(deg, stmp, blocksum, n);
    k_scanC<<<NB, 256, 0, stream>>>(stmp, blocksum, offs, cursor, n, P, NB);
    k_scatter<<<(P + 255) / 256, 256, 0, stream>>>(src, dst, cursor, csr, E, n);

    // layer 1 (gemm1 fuses attention logits)
    k_gemm1<<<(n + 127) / 128, 256, 0, stream>>>(x, W1t, h1b, asrc1, adst1, als1, ald1, n);
    k_agg1<<<n, 128, 0, stream>>>(csr, offs, als1, ald1, h1b, b1, x2b);

    // layer 2
    k_gemm2<<<(n + 63) / 64, 256, 0, stream>>>(x2b, W2t, asrc2, adst2, h2b, als2, ald2, n);
    k_agg2<<<(n + 3) / 4, 256, 0, stream>>>(csr, offs, als2, ald2, h2b, b2, out, n);
}

// Round 11
// 339.966 us; speedup vs baseline: 1.0423x; 1.0423x over previous
//
#include <hip/hip_runtime.h>
#include <hip/hip_bf16.h>

// GATNet v10: v9's al-fusion kept, but gemm1 reverted to the 128x128/acc[4][4]
// tile (v9's 256-wide acc[4][8] cost ~128 acc VGPRs -> occupancy collapse,
// 333->354us). Each wave's 64-col span = 2 whole heads, so exact fp32 logits
// still come free in the epilogue. k_al1 remains deleted.

#define LRELU(x) ((x) > 0.f ? (x) : 0.2f * (x))

typedef __attribute__((ext_vector_type(8))) short short8;
typedef __attribute__((ext_vector_type(8))) unsigned short ushort8;
typedef __attribute__((ext_vector_type(4))) float f32x4;

__device__ inline unsigned short f2b(float f) {
    __hip_bfloat16 h = __float2bfloat16(f);
    return *reinterpret_cast<unsigned short*>(&h);
}
__device__ inline float b2f(unsigned short u) {
    __hip_bfloat16 h;
    *reinterpret_cast<unsigned short*>(&h) = u;
    return __bfloat162float(h);
}

// ---------------- fused prep: hist + W1 transpose-cast + W2 transpose-cast --

__global__ __launch_bounds__(256) void k_prep(const int* __restrict__ dst, int* deg, int E,
                                              const float* __restrict__ W1,
                                              unsigned short* __restrict__ W1t,
                                              const float* __restrict__ W2,
                                              unsigned short* __restrict__ W2t,
                                              int HB) {
    int b = blockIdx.x, t = threadIdx.x;
    if (b < HB) {
        int i = b * 256 + t;
        if (i < E) atomicAdd(&deg[dst[i]], 1);
    } else if (b < HB + 256) {
        int k = b - HB;
        W1t[t * 256 + k] = f2b(W1[k * 256 + t]);
    } else {
        int nn = b - HB - 256;  // 0..15
        W2t[nn * 256 + t] = f2b(W2[t * 16 + nn]);
    }
}

// ---------------- scan phase A: block-local ----------------

__global__ __launch_bounds__(256) void k_scanA(const int* __restrict__ deg,
                                               int* __restrict__ tmp,
                                               int* __restrict__ blocksum, int n) {
    __shared__ int sc[256];
    int b = blockIdx.x, t = threadIdx.x;
    int i = b * 256 + t;
    int v = (i < n) ? deg[i] + 1 : 0;   // +1: self loop
    sc[t] = v;
    __syncthreads();
    for (int off = 1; off < 256; off <<= 1) {
        int x = 0;
        if (t >= off) x = sc[t - off];
        __syncthreads();
        sc[t] += x;
        __syncthreads();
    }
    if (i < n) tmp[i] = sc[t] - v;
    if (t == 255) blocksum[b] = sc[255];
}

// ---------------- scan phase B+C merged ----------------

__global__ __launch_bounds__(256) void k_scanC(const int* __restrict__ tmp,
                                               const int* __restrict__ blocksum,
                                               int* __restrict__ offs,
                                               int* __restrict__ cursor,
                                               int n, int P, int nb) {
    __shared__ int sc[256];
    __shared__ int base;
    int b = blockIdx.x, t = threadIdx.x;
    int v = (t < nb) ? blocksum[t] : 0;
    sc[t] = v;
    __syncthreads();
    for (int off = 1; off < 256; off <<= 1) {
        int x = 0;
        if (t >= off) x = sc[t - off];
        __syncthreads();
        sc[t] += x;
        __syncthreads();
    }
    if (t == 0) base = (b == 0) ? 0 : sc[b - 1];
    __syncthreads();
    int i = b * 256 + t;
    if (i < n) {
        int o = tmp[i] + base;
        offs[i] = o;
        cursor[i] = o;
    }
    if (b == 0 && t == 0) offs[n] = P;
}

__global__ void k_scatter(const int* __restrict__ src, const int* __restrict__ dst,
                          int* cursor, int* __restrict__ csr, int E, int n) {
    int i = blockIdx.x * blockDim.x + threadIdx.x;
    int s, d;
    if (i < E) {
        s = src[i];
        d = dst[i];
    } else if (i < E + n) {
        s = i - E;
        d = s;
    } else {
        return;
    }
    int p = atomicAdd(&cursor[d], 1);
    csr[p] = s;
}

// ---------------- GEMM1 (MFMA bf16) 128x128/block + fused al logits ---------
// v8 tiling (acc[4][4]); wave w covers 64 cols = 2 whole heads, so als/ald
// computed exactly from fp32 acc via width-16 shuffle reduce, no atomics.

__global__ __launch_bounds__(256) void k_gemm1(const float* __restrict__ A,
                                               const unsigned short* __restrict__ Wt,
                                               unsigned short* __restrict__ h1b,
                                               const float* __restrict__ asrc,
                                               const float* __restrict__ adst,
                                               float* __restrict__ als,
                                               float* __restrict__ ald, int M) {
    __shared__ unsigned short As[128][40];
    __shared__ unsigned short Bs[128][40];
    int t = threadIdx.x;
    int r0 = blockIdx.x * 128, c0 = blockIdx.y * 128;
    int srow = t >> 1, shalf = t & 1;
    int lane = t & 63, w = t >> 6;
    int lane15 = lane & 15, quad = lane >> 4;
    int rbw = (w & 1) * 64, cbw = (w >> 1) * 64;

    f32x4 acc[4][4];
#pragma unroll
    for (int i = 0; i < 4; i++)
#pragma unroll
        for (int j = 0; j < 4; j++) acc[i][j] = (f32x4)0.f;

    for (int k0 = 0; k0 < 256; k0 += 32) {
        {
            int row = r0 + srow;
            ushort8 p0, p1;
            if (row < M) {
                const float4* sp = (const float4*)&A[(size_t)row * 256 + k0 + shalf * 16];
                float4 f0 = sp[0], f1 = sp[1], f2 = sp[2], f3 = sp[3];
                p0[0] = f2b(f0.x); p0[1] = f2b(f0.y); p0[2] = f2b(f0.z); p0[3] = f2b(f0.w);
                p0[4] = f2b(f1.x); p0[5] = f2b(f1.y); p0[6] = f2b(f1.z); p0[7] = f2b(f1.w);
                p1[0] = f2b(f2.x); p1[1] = f2b(f2.y); p1[2] = f2b(f2.z); p1[3] = f2b(f2.w);
                p1[4] = f2b(f3.x); p1[5] = f2b(f3.y); p1[6] = f2b(f3.z); p1[7] = f2b(f3.w);
            } else {
                p0 = (ushort8)0; p1 = (ushort8)0;
            }
            *(ushort8*)&As[srow][shalf * 16] = p0;
            *(ushort8*)&As[srow][shalf * 16 + 8] = p1;
            const ushort8* bp = (const ushort8*)&Wt[(size_t)(c0 + srow) * 256 + k0 + shalf * 16];
            *(ushort8*)&Bs[srow][shalf * 16] = bp[0];
            *(ushort8*)&Bs[srow][shalf * 16 + 8] = bp[1];
        }
        __syncthreads();
        short8 af[4], bf[4];
#pragma unroll
        for (int i = 0; i < 4; i++)
            af[i] = *(const short8*)&As[rbw + i * 16 + lane15][quad * 8];
#pragma unroll
        for (int j = 0; j < 4; j++)
            bf[j] = *(const short8*)&Bs[cbw + j * 16 + lane15][quad * 8];
#pragma unroll
        for (int i = 0; i < 4; i++)
#pragma unroll
            for (int j = 0; j < 4; j++)
                acc[i][j] = __builtin_amdgcn_mfma_f32_16x16x32_bf16(af[i], bf[j], acc[i][j], 0, 0, 0);
        __syncthreads();
    }

    // epilogue: h1b writes + exact attention logits for this wave's 2 heads
    float asv[4], adv[4];
#pragma unroll
    for (int j = 0; j < 4; j++) {
        asv[j] = asrc[c0 + cbw + j * 16 + lane15];
        adv[j] = adst[c0 + cbw + j * 16 + lane15];
    }
    int hb = (c0 + cbw) >> 5;   // first of the wave's 2 heads
#pragma unroll
    for (int i = 0; i < 4; i++) {
        int rowb = r0 + rbw + i * 16 + quad * 4;
#pragma unroll
        for (int j = 0; j < 4; j++) {
            int col = c0 + cbw + j * 16 + lane15;
#pragma unroll
            for (int r = 0; r < 4; r++) {
                int row = rowb + r;
                if (row < M) h1b[(size_t)row * 256 + col] = f2b(acc[i][j][r]);
            }
        }
#pragma unroll
        for (int m = 0; m < 2; m++) {
#pragma unroll
            for (int r = 0; r < 4; r++) {
                float ps = acc[i][2 * m][r] * asv[2 * m] + acc[i][2 * m + 1][r] * asv[2 * m + 1];
                float pd = acc[i][2 * m][r] * adv[2 * m] + acc[i][2 * m + 1][r] * adv[2 * m + 1];
#pragma unroll
                for (int off = 1; off < 16; off <<= 1) {
                    ps += __shfl_xor(ps, off, 16);
                    pd += __shfl_xor(pd, off, 16);
                }
                int row = rowb + r;
                if (lane15 == 0 && row < M) {
                    als[(size_t)row * 8 + hb + m] = ps;
                    ald[(size_t)row * 8 + hb + m] = pd;
                }
            }
        }
    }
}

// ---------------- layer-1 aggregate: fused weights, 4-deep gather pipeline --

__global__ __launch_bounds__(128) void k_agg1(const int* __restrict__ csr,
                                              const int* __restrict__ offs,
                                              const float* __restrict__ als,
                                              const float* __restrict__ aldg,
                                              const unsigned short* __restrict__ h1b,
                                              const float* __restrict__ b1,
                                              unsigned short* __restrict__ x2b) {
    int v = blockIdx.x;
    int t = threadIdx.x;           // cols 2t,2t+1; head = t>>4
    int start = offs[v];
    int deg = offs[v + 1] - start;
    __shared__ float aldv[8];
    __shared__ int su[32];
    __shared__ float ws[8 * 33];
    if (t < 8) aldv[t] = aldg[v * 8 + t];
    __syncthreads();
    int h = t >> 4;
    const unsigned int* __restrict__ hbase = (const unsigned int*)h1b;
    float a0 = 0.f, a1 = 0.f, wsum = 0.f;
    for (int base = 0; base < deg; base += 32) {
        int cnt = min(32, deg - base);
        int cnt4 = (cnt + 3) & ~3;
        if (base) __syncthreads();
        if (t < cnt4) {
            if (t < cnt) {
                int u = csr[start + base + t];
                su[t] = u;
                const float4* ap = (const float4*)(als + (size_t)u * 8);
                float4 x0 = ap[0], x1 = ap[1];
                ws[0 * 33 + t] = __expf(LRELU(x0.x + aldv[0]));
                ws[1 * 33 + t] = __expf(LRELU(x0.y + aldv[1]));
                ws[2 * 33 + t] = __expf(LRELU(x0.z + aldv[2]));
                ws[3 * 33 + t] = __expf(LRELU(x0.w + aldv[3]));
                ws[4 * 33 + t] = __expf(LRELU(x1.x + aldv[4]));
                ws[5 * 33 + t] = __expf(LRELU(x1.y + aldv[5]));
                ws[6 * 33 + t] = __expf(LRELU(x1.z + aldv[6]));
                ws[7 * 33 + t] = __expf(LRELU(x1.w + aldv[7]));
            } else {
                su[t] = v;
#pragma unroll
                for (int k = 0; k < 8; k++) ws[k * 33 + t] = 0.f;
            }
        }
        __syncthreads();
        for (int e = 0; e < cnt4; e += 4) {
            int u0 = su[e + 0], u1 = su[e + 1], u2 = su[e + 2], u3 = su[e + 3];
            float w0 = ws[h * 33 + e + 0];
            float w1 = ws[h * 33 + e + 1];
            float w2 = ws[h * 33 + e + 2];
            float w3 = ws[h * 33 + e + 3];
            unsigned int pk0 = hbase[u0 * 128 + t];
            unsigned int pk1 = hbase[u1 * 128 + t];
            unsigned int pk2 = hbase[u2 * 128 + t];
            unsigned int pk3 = hbase[u3 * 128 + t];
            a0 += w0 * __uint_as_float(pk0 << 16);
            a1 += w0 * __uint_as_float(pk0 & 0xffff0000u);
            a0 += w1 * __uint_as_float(pk1 << 16);
            a1 += w1 * __uint_as_float(pk1 & 0xffff0000u);
            a0 += w2 * __uint_as_float(pk2 << 16);
            a1 += w2 * __uint_as_float(pk2 & 0xffff0000u);
            a0 += w3 * __uint_as_float(pk3 << 16);
            a1 += w3 * __uint_as_float(pk3 & 0xffff0000u);
            wsum += (w0 + w1) + (w2 + w3);
        }
    }
    const float2* b1v = (const float2*)b1;
    float2 bb = b1v[t];
    float inv = 1.0f / wsum;
    float o0 = a0 * inv + bb.x;
    float o1 = a1 * inv + bb.y;
    o0 = o0 > 0.f ? o0 : 0.f;
    o1 = o1 > 0.f ? o1 : 0.f;
    unsigned int opk = (unsigned int)f2b(o0) | ((unsigned int)f2b(o1) << 16);
    ((unsigned int*)(x2b + (size_t)v * 256))[t] = opk;
}

// ---------------- GEMM2 (MFMA) + fused layer-2 logits ----------------------

__global__ __launch_bounds__(256) void k_gemm2(const unsigned short* __restrict__ Xb,
                                               const unsigned short* __restrict__ W2t,
                                               const float* __restrict__ asrc,
                                               const float* __restrict__ adst,
                                               unsigned short* __restrict__ h2b,
                                               float* __restrict__ als,
                                               float* __restrict__ ald, int n) {
    int t = threadIdx.x;
    int lane = t & 63, w = t >> 6;
    int lane15 = lane & 15, quad = lane >> 4;
    int row0 = blockIdx.x * 64 + w * 16;
    f32x4 acc = (f32x4)0.f;
#pragma unroll
    for (int k0 = 0; k0 < 256; k0 += 32) {
        short8 a = *(const short8*)&Xb[(size_t)(row0 + lane15) * 256 + k0 + quad * 8];
        short8 b = *(const short8*)&W2t[lane15 * 256 + k0 + quad * 8];
        acc = __builtin_amdgcn_mfma_f32_16x16x32_bf16(a, b, acc, 0, 0, 0);
    }
    float asv = asrc[lane15], adv = adst[lane15];
#pragma unroll
    for (int r = 0; r < 4; r++) {
        int row = row0 + quad * 4 + r;
        float hv = acc[r];
        float ps = hv * asv, pd = hv * adv;
#pragma unroll
        for (int off = 1; off < 16; off <<= 1) {
            ps += __shfl_xor(ps, off, 16);
            pd += __shfl_xor(pd, off, 16);
        }
        if (row < n) {
            h2b[(size_t)row * 16 + lane15] = f2b(hv);
            if (lane15 == 0) {
                als[row] = ps;
                ald[row] = pd;
            }
        }
    }
}

// ---------------- layer-2 aggregate (fused w) + log_softmax -----------------

__global__ __launch_bounds__(256) void k_agg2(const int* __restrict__ csr,
                                              const int* __restrict__ offs,
                                              const float* __restrict__ als,
                                              const float* __restrict__ aldg,
                                              const unsigned short* __restrict__ h2b,
                                              const float* __restrict__ b2,
                                              float* __restrict__ out, int n) {
    int v = blockIdx.x * 4 + (threadIdx.x >> 6);
    if (v >= n) return;
    int lane = threadIdx.x & 63;
    int start = offs[v];
    int deg = offs[v + 1] - start;
    float aldv = aldg[v];
    int c = lane & 15, q = lane >> 4;
    float acc = 0.f, wsum = 0.f;
    for (int e = q; e < deg; e += 4) {
        int u = csr[start + e];
        float x = als[u] + aldv;
        float wv = __expf(LRELU(x));
        acc += wv * b2f(h2b[(size_t)u * 16 + c]);
        wsum += wv;
    }
    acc += __shfl_xor(acc, 32, 64);
    acc += __shfl_xor(acc, 16, 64);
    wsum += __shfl_xor(wsum, 32, 64);
    wsum += __shfl_xor(wsum, 16, 64);
    float o = acc / wsum + b2[c];
    float mx = o;
#pragma unroll
    for (int off = 8; off; off >>= 1) mx = fmaxf(mx, __shfl_xor(mx, off, 16));
    float s = __expf(o - mx);
#pragma unroll
    for (int off = 8; off; off >>= 1) s += __shfl_xor(s, off, 16);
    float res = o - mx - __logf(s);
    if (q == 0) out[(size_t)v * 16 + c] = res;
}

// ---------------- launch ----------------

extern "C" void kernel_launch(void* const* d_in, const int* in_sizes, int n_in,
                              void* d_out, int out_size, void* d_ws, size_t ws_size,
                              hipStream_t stream) {
    const float* x = (const float*)d_in[0];
    const int* ei = (const int*)d_in[1];
    const float* W1 = (const float*)d_in[2];
    const float* asrc1 = (const float*)d_in[3];
    const float* adst1 = (const float*)d_in[4];
    const float* b1 = (const float*)d_in[5];
    const float* W2 = (const float*)d_in[6];
    const float* asrc2 = (const float*)d_in[7];
    const float* adst2 = (const float*)d_in[8];
    const float* b2 = (const float*)d_in[9];
    float* out = (float*)d_out;

    int n = in_sizes[0] / 256;   // 50000
    int E = in_sizes[1] / 2;     // 800000
    int P = E + n;
    const int* src = ei;
    const int* dst = ei + E;
    int NB = (n + 255) / 256;    // 196
    int HB = (E + 255) / 256;    // 3125

    char* p = (char*)d_ws;
    auto alloc = [&](size_t bytes) {
        void* r = (void*)p;
        p += (bytes + 255) & ~(size_t)255;
        return r;
    };
    unsigned short* h1b = (unsigned short*)alloc((size_t)n * 256 * 2);
    unsigned short* x2b = (unsigned short*)alloc((size_t)n * 256 * 2);
    unsigned short* W1t = (unsigned short*)alloc((size_t)256 * 256 * 2);
    unsigned short* W2t = (unsigned short*)alloc((size_t)16 * 256 * 2);
    float* als1 = (float*)alloc((size_t)n * 8 * 4);
    float* ald1 = (float*)alloc((size_t)n * 8 * 4);
    unsigned short* h2b = (unsigned short*)alloc((size_t)n * 16 * 2);
    float* als2 = (float*)alloc((size_t)n * 4);
    float* ald2 = (float*)alloc((size_t)n * 4);
    int* deg = (int*)alloc((size_t)n * 4);
    int* offs = (int*)alloc((size_t)(n + 1) * 4);
    int* cursor = (int*)alloc((size_t)n * 4);
    int* stmp = (int*)alloc((size_t)n * 4);
    int* blocksum = (int*)alloc((size_t)NB * 4);
    int* csr = (int*)alloc((size_t)P * 4);

    // CSR build + weight prep (fused)
    hipMemsetAsync(deg, 0, (size_t)n * 4, stream);
    k_prep<<<HB + 256 + 16, 256, 0, stream>>>(dst, deg, E, W1, W1t, W2, W2t, HB);
    k_scanA<<<NB, 256, 0, stream>>>(deg, stmp, blocksum, n);
    k_scanC<<<NB, 256, 0, stream>>>(stmp, blocksum, offs, cursor, n, P, NB);
    k_scatter<<<(P + 255) / 256, 256, 0, stream>>>(src, dst, cursor, csr, E, n);

    // layer 1 (gemm1 fuses attention logits)
    k_gemm1<<<dim3((n + 127) / 128, 2), 256, 0, stream>>>(x, W1t, h1b, asrc1, adst1, als1, ald1, n);
    k_agg1<<<n, 128, 0, stream>>>(csr, offs, als1, ald1, h1b, b1, x2b);

    // layer 2
    k_gemm2<<<(n + 63) / 64, 256, 0, stream>>>(x2b, W2t, asrc2, adst2, h2b, als2, ald2, n);
    k_agg2<<<(n + 3) / 4, 256, 0, stream>>>(csr, offs, als2, ald2, h2b, b2, out, n);
}